// Round 1
// baseline (210.215 us; speedup 1.0000x reference)
//
#include <hip/hip_runtime.h>

#define BQ 8
#define NQ 2048
#define ROWS 8      // i-rows per block
#define TPB 256
#define NBLK (BQ * (NQ / ROWS))   // 2048 blocks

__global__ __launch_bounds__(TPB) void idla_main(
        const float* __restrict__ preds,
        const float* __restrict__ targets,
        const float* __restrict__ adj,
        float2* __restrict__ partials) {
    // SoA point stage: 6 * 2048 * 4 B = 48 KB LDS (-> 3 blocks/CU)
    __shared__ __attribute__((aligned(16))) float px[NQ], py[NQ], pz[NQ];
    __shared__ __attribute__((aligned(16))) float tx[NQ], ty[NQ], tz[NQ];
    __shared__ float red_sq[TPB / 64], red_ad[TPB / 64];

    const int nb_per_batch = NQ / ROWS;               // 256
    const int b  = blockIdx.x / nb_per_batch;
    const int i0 = (blockIdx.x % nb_per_batch) * ROWS;
    const int tid = threadIdx.x;

    // Stage this batch's points into LDS (AoS global -> SoA LDS), coalesced dwords
    const float* pb = preds   + (size_t)b * NQ * 3;
    const float* tb = targets + (size_t)b * NQ * 3;
    for (int e = tid; e < NQ * 3; e += TPB) {
        int j = e / 3;                 // const divisor -> mulhi, no v_div
        int c = e - 3 * j;
        float v = pb[e];
        float w = tb[e];
        if (c == 0)      { px[j] = v; tx[j] = w; }
        else if (c == 1) { py[j] = v; ty[j] = w; }
        else             { pz[j] = v; tz[j] = w; }
    }
    __syncthreads();

    float acc_sq = 0.0f;   // sum of ((dp - dt) * a)^2
    float acc_ad = 0.0f;   // sum of a
    const float* adjb = adj + (size_t)b * NQ * NQ;

    #pragma unroll
    for (int ig = 0; ig < ROWS; ig += 4) {
        // Register-cache 4 i-points (broadcast LDS reads: all lanes same addr)
        float pix[4], piy[4], piz[4], tix[4], tiy[4], tiz[4];
        #pragma unroll
        for (int ii = 0; ii < 4; ii++) {
            int i = i0 + ig + ii;
            pix[ii] = px[i]; piy[ii] = py[i]; piz[ii] = pz[i];
            tix[ii] = tx[i]; tiy[ii] = ty[i]; tiz[ii] = tz[i];
        }
        // Sweep j with float4 granularity; 2048 / (256*4) = 2 iterations
        for (int j0 = tid * 4; j0 < NQ; j0 += TPB * 4) {
            float4 vx = *(const float4*)&px[j0];
            float4 vy = *(const float4*)&py[j0];
            float4 vz = *(const float4*)&pz[j0];
            float4 wx = *(const float4*)&tx[j0];
            float4 wy = *(const float4*)&ty[j0];
            float4 wz = *(const float4*)&tz[j0];
            float jx[4] = {vx.x, vx.y, vx.z, vx.w};
            float jy[4] = {vy.x, vy.y, vy.z, vy.w};
            float jz[4] = {vz.x, vz.y, vz.z, vz.w};
            float ux[4] = {wx.x, wx.y, wx.z, wx.w};
            float uy[4] = {wy.x, wy.y, wy.z, wy.w};
            float uz[4] = {wz.x, wz.y, wz.z, wz.w};

            #pragma unroll
            for (int ii = 0; ii < 4; ii++) {
                int i = i0 + ig + ii;
                float4 a4 = *(const float4*)&adjb[(size_t)i * NQ + j0];
                float av[4] = {a4.x, a4.y, a4.z, a4.w};
                #pragma unroll
                for (int jj = 0; jj < 4; jj++) {
                    float dx = pix[ii] - jx[jj];
                    float dy = piy[ii] - jy[jj];
                    float dz = piz[ii] - jz[jj];
                    float sp = fmaf(dx, dx, fmaf(dy, dy, dz * dz)); // dp^2
                    float ex = tix[ii] - ux[jj];
                    float ey = tiy[ii] - uy[jj];
                    float ez = tiz[ii] - uz[jj];
                    float st = fmaf(ex, ex, fmaf(ey, ey, ez * ez)); // dt^2
                    // (dp - dt)^2 = sp + st - 2*sqrt(sp*st): ONE v_sqrt_f32
                    float r  = __builtin_amdgcn_sqrtf(sp * st);
                    float t  = fmaf(-2.0f, r, sp + st);
                    float aa = av[jj] * av[jj];          // exact ((..)*a)^2 semantics
                    acc_sq = fmaf(t, aa, acc_sq);
                    acc_ad += av[jj];
                }
            }
        }
    }

    // Wave64 shuffle reduction
    #pragma unroll
    for (int off = 32; off > 0; off >>= 1) {
        acc_sq += __shfl_down(acc_sq, off, 64);
        acc_ad += __shfl_down(acc_ad, off, 64);
    }
    const int wave = tid >> 6;
    if ((tid & 63) == 0) { red_sq[wave] = acc_sq; red_ad[wave] = acc_ad; }
    __syncthreads();
    if (tid == 0) {
        float s_sq = 0.0f, s_ad = 0.0f;
        #pragma unroll
        for (int w = 0; w < TPB / 64; w++) { s_sq += red_sq[w]; s_ad += red_ad[w]; }
        // NO atomics: per-block partial, reduced by the second dispatch
        partials[blockIdx.x] = make_float2(s_sq, s_ad);
    }
}

__global__ __launch_bounds__(256) void idla_reduce(
        const float2* __restrict__ partials, float* __restrict__ out) {
    double s = 0.0, a = 0.0;
    for (int i = threadIdx.x; i < NBLK; i += 256) {
        float2 p = partials[i];
        s += (double)p.x;
        a += (double)p.y;
    }
    #pragma unroll
    for (int off = 32; off > 0; off >>= 1) {
        s += __shfl_down(s, off, 64);
        a += __shfl_down(a, off, 64);
    }
    __shared__ double rs[4], ra[4];
    const int wave = threadIdx.x >> 6;
    if ((threadIdx.x & 63) == 0) { rs[wave] = s; ra[wave] = a; }
    __syncthreads();
    if (threadIdx.x == 0) {
        double ts = rs[0] + rs[1] + rs[2] + rs[3];
        double ta = ra[0] + ra[1] + ra[2] + ra[3];
        out[0] = (float)(ts / ta);
    }
}

extern "C" void kernel_launch(void* const* d_in, const int* in_sizes, int n_in,
                              void* d_out, int out_size, void* d_ws, size_t ws_size,
                              hipStream_t stream) {
    const float* preds   = (const float*)d_in[0];
    const float* targets = (const float*)d_in[1];
    const float* adj     = (const float*)d_in[2];
    float2* partials = (float2*)d_ws;   // needs NBLK*8 = 16 KB of workspace
    float*  out      = (float*)d_out;

    hipLaunchKernelGGL(idla_main, dim3(NBLK), dim3(TPB), 0, stream,
                       preds, targets, adj, partials);
    hipLaunchKernelGGL(idla_reduce, dim3(1), dim3(256), 0, stream, partials, out);
}

// Round 2
// 194.163 us; speedup vs baseline: 1.0827x; 1.0827x over previous
//
#include <hip/hip_runtime.h>

#define BQ 8
#define NQ 2048
#define ROWS 8      // i-rows per block
#define TPB 256
#define NBLK (BQ * (NQ / ROWS))   // 2048 blocks
#define JTILE (TPB * 4)           // j covered per sweep: 1024
#define NJT (NQ / JTILE)          // 2 sweeps

__global__ __launch_bounds__(TPB, 4) void idla_main(
        const float* __restrict__ preds,
        const float* __restrict__ targets,
        const float* __restrict__ adj,
        float2* __restrict__ partials) {
    // NO point staging: points are 49 KB/batch, L2-resident (re-read 256x).
    // LDS only for the tiny cross-wave reduction -> occupancy is VGPR-bound.
    __shared__ float red_sq[TPB / 64], red_ad[TPB / 64];

    const int nb_per_batch = NQ / ROWS;               // 256
    const int b  = blockIdx.x / nb_per_batch;
    const int i0 = (blockIdx.x % nb_per_batch) * ROWS;
    const int tid = threadIdx.x;

    const float* pb   = preds   + (size_t)b * NQ * 3;
    const float* tb   = targets + (size_t)b * NQ * 3;
    const float* adjb = adj     + (size_t)b * NQ * NQ;

    float acc_sq = 0.0f;   // sum of ((dp - dt) * a)^2
    float acc_ad = 0.0f;   // sum of a

    #pragma unroll
    for (int jt = 0; jt < NJT; ++jt) {
        const int j0 = jt * JTILE + tid * 4;
        // 4 consecutive j-points = 12 contiguous floats = 3x float4, coalesced,
        // straight from AoS global (L2 hit). Unpack in registers.
        const float4* pj = (const float4*)(pb + 3 * j0);
        const float4* tj = (const float4*)(tb + 3 * j0);
        float4 f0 = pj[0], f1 = pj[1], f2 = pj[2];
        float4 g0 = tj[0], g1 = tj[1], g2 = tj[2];
        float jx[4] = {f0.x, f0.w, f1.z, f2.y};
        float jy[4] = {f0.y, f1.x, f1.w, f2.z};
        float jz[4] = {f0.z, f1.y, f2.x, f2.w};
        float ux[4] = {g0.x, g0.w, g1.z, g2.y};
        float uy[4] = {g0.y, g1.x, g1.w, g2.z};
        float uz[4] = {g0.z, g1.y, g2.x, g2.w};

        // Batch all ROWS adj loads first: 8 KB in flight per wave (MLP).
        float4 a4[ROWS];
        #pragma unroll
        for (int r = 0; r < ROWS; ++r)
            a4[r] = *(const float4*)&adjb[(size_t)(i0 + r) * NQ + j0];

        #pragma unroll
        for (int r = 0; r < ROWS; ++r) {
            // i-point coords: block-uniform addresses -> scalar loads, L2-hit.
            const int i = i0 + r;
            const float pix = pb[3*i], piy = pb[3*i+1], piz = pb[3*i+2];
            const float tix = tb[3*i], tiy = tb[3*i+1], tiz = tb[3*i+2];
            float av[4] = {a4[r].x, a4[r].y, a4[r].z, a4[r].w};
            #pragma unroll
            for (int jj = 0; jj < 4; ++jj) {
                float dx = pix - jx[jj];
                float dy = piy - jy[jj];
                float dz = piz - jz[jj];
                float sp = fmaf(dx, dx, fmaf(dy, dy, dz * dz)); // dp^2
                float ex = tix - ux[jj];
                float ey = tiy - uy[jj];
                float ez = tiz - uz[jj];
                float st = fmaf(ex, ex, fmaf(ey, ey, ez * ez)); // dt^2
                // (dp - dt)^2 = sp + st - 2*sqrt(sp*st): ONE v_sqrt_f32
                float rt = __builtin_amdgcn_sqrtf(sp * st);
                float t  = fmaf(-2.0f, rt, sp + st);
                float aa = av[jj] * av[jj];
                acc_sq = fmaf(t, aa, acc_sq);
                acc_ad += av[jj];
            }
        }
    }

    // Wave64 shuffle reduction
    #pragma unroll
    for (int off = 32; off > 0; off >>= 1) {
        acc_sq += __shfl_down(acc_sq, off, 64);
        acc_ad += __shfl_down(acc_ad, off, 64);
    }
    const int wave = tid >> 6;
    if ((tid & 63) == 0) { red_sq[wave] = acc_sq; red_ad[wave] = acc_ad; }
    __syncthreads();
    if (tid == 0) {
        float s_sq = 0.0f, s_ad = 0.0f;
        #pragma unroll
        for (int w = 0; w < TPB / 64; w++) { s_sq += red_sq[w]; s_ad += red_ad[w]; }
        partials[blockIdx.x] = make_float2(s_sq, s_ad);
    }
}

__global__ __launch_bounds__(256) void idla_reduce(
        const float2* __restrict__ partials, float* __restrict__ out) {
    double s = 0.0, a = 0.0;
    for (int i = threadIdx.x; i < NBLK; i += 256) {
        float2 p = partials[i];
        s += (double)p.x;
        a += (double)p.y;
    }
    #pragma unroll
    for (int off = 32; off > 0; off >>= 1) {
        s += __shfl_down(s, off, 64);
        a += __shfl_down(a, off, 64);
    }
    __shared__ double rs[4], ra[4];
    const int wave = threadIdx.x >> 6;
    if ((threadIdx.x & 63) == 0) { rs[wave] = s; ra[wave] = a; }
    __syncthreads();
    if (threadIdx.x == 0) {
        double ts = rs[0] + rs[1] + rs[2] + rs[3];
        double ta = ra[0] + ra[1] + ra[2] + ra[3];
        out[0] = (float)(ts / ta);
    }
}

extern "C" void kernel_launch(void* const* d_in, const int* in_sizes, int n_in,
                              void* d_out, int out_size, void* d_ws, size_t ws_size,
                              hipStream_t stream) {
    const float* preds   = (const float*)d_in[0];
    const float* targets = (const float*)d_in[1];
    const float* adj     = (const float*)d_in[2];
    float2* partials = (float2*)d_ws;   // NBLK * 8 B = 16 KB of workspace
    float*  out      = (float*)d_out;

    hipLaunchKernelGGL(idla_main, dim3(NBLK), dim3(TPB), 0, stream,
                       preds, targets, adj, partials);
    hipLaunchKernelGGL(idla_reduce, dim3(1), dim3(256), 0, stream, partials, out);
}